// Round 1
// baseline (1833.086 us; speedup 1.0000x reference)
//
#include <hip/hip_runtime.h>
#include <cmath>

#define S       65
#define SP      66              // padded row stride (floats)
#define REC     (S*SP)          // 4290 floats per matrix record
#define VOCAB   1024
#define EMS     68              // em_pT row stride
#define NTH     256
#define RT      4               // rows per thread tile
#define CTN     5               // cols per thread tile
#define CTILES  13              // 13*5 = 65 cols
#define RTILES  17              // 17 row tiles (rows 0..64, last overlaps)
#define PSEG    768             // segment blocks (3 per CU)
#define GROUP   12
#define NGROUPS (PSEG/GROUP)    // 64

__device__ __forceinline__ float wave_max(float v) {
  #pragma unroll
  for (int o = 32; o > 0; o >>= 1) v = fmaxf(v, __shfl_xor(v, o));
  return v;
}
__device__ __forceinline__ float wave_sumf(float v) {
  #pragma unroll
  for (int o = 32; o > 0; o >>= 1) v += __shfl_xor(v, o);
  return v;
}
__device__ __forceinline__ int wave_sumi(int v) {
  #pragma unroll
  for (int o = 32; o > 0; o >>= 1) v += __shfl_xor(v, o);
  return v;
}

// 65x65x65 fp32 matmul tile: thread computes RT x CTN outputs.
__device__ __forceinline__ void mm_tile(const float* Rl, const float* Cl,
                                        int r0, int c0, float acc[RT][CTN]) {
  #pragma unroll 5
  for (int j = 0; j < S; ++j) {
    float cv[CTN];
    #pragma unroll
    for (int u = 0; u < CTN; ++u) cv[u] = Cl[j*SP + c0 + u];
    #pragma unroll
    for (int q = 0; q < RT; ++q) {
      float rv = Rl[(r0+q)*SP + j];
      #pragma unroll
      for (int u = 0; u < CTN; ++u) acc[q][u] = fmaf(rv, cv[u], acc[q][u]);
    }
  }
}

// ---------- K1a: row softmax of log_trans -> transition probs a_prob[65][66]
__global__ void k_trans_prep(const float* __restrict__ lt, float* __restrict__ a_prob) {
  int i = blockIdx.x, t = threadIdx.x;           // 64 threads, one wave
  float x0 = lt[i*S + t];
  float x1 = (t == 0) ? lt[i*S + 64] : -1e30f;
  float m = wave_max(fmaxf(x0, x1));
  float e0 = expf(x0 - m);
  float e1 = (t == 0) ? expf(x1 - m) : 0.f;
  float ssum = wave_sumf(e0 + e1);
  float inv = 1.f / ssum;
  a_prob[i*SP + t] = e0 * inv;
  if (t == 0) { a_prob[i*SP + 64] = e1 * inv; a_prob[i*SP + 65] = 0.f; }
}

// ---------- K1b: row softmax of log_em -> em_pT[v][j] (transposed), stride EMS
__global__ __launch_bounds__(NTH) void k_em_prep(const float* __restrict__ le,
                                                 float* __restrict__ em_pT) {
  int j = blockIdx.x, t = threadIdx.x;
  const float* row = le + (size_t)j * VOCAB;
  float x[4];
  float m = -1e30f;
  #pragma unroll
  for (int q = 0; q < 4; ++q) { x[q] = row[t + 256*q]; m = fmaxf(m, x[q]); }
  m = wave_max(m);
  __shared__ float wred[4], wsum[4];
  int w = t >> 6, lane = t & 63;
  if (lane == 0) wred[w] = m;
  __syncthreads();
  m = fmaxf(fmaxf(wred[0], wred[1]), fmaxf(wred[2], wred[3]));
  float s = 0.f;
  #pragma unroll
  for (int q = 0; q < 4; ++q) s += expf(x[q] - m);
  s = wave_sumf(s);
  if (lane == 0) wsum[w] = s;
  __syncthreads();
  float inv = 1.f / (wsum[0] + wsum[1] + wsum[2] + wsum[3]);
  #pragma unroll
  for (int q = 0; q < 4; ++q)
    em_pT[(size_t)(t + 256*q) * EMS + j] = expf(x[q] - m) * inv;
}

// ---------- K2: pair table C_v = A * diag(e_v) * A   (1024 blocks)
__global__ __launch_bounds__(NTH) void k_pair(const float* __restrict__ a_prob,
                                              const float* __restrict__ em_pT,
                                              float* __restrict__ Ctab) {
  __shared__ __align__(16) float aL[REC];
  __shared__ __align__(16) float bL[REC];
  int v = blockIdx.x, t = threadIdx.x;
  for (int u = t; u < REC; u += NTH) aL[u] = a_prob[u];
  __syncthreads();
  for (int u = t; u < REC; u += NTH) {
    int j = u / SP;
    bL[u] = em_pT[(size_t)v * EMS + j] * aL[u];
  }
  __syncthreads();
  int rt = t / CTILES, ct = t - rt*CTILES;
  bool act = rt < RTILES;
  int r0 = (rt >= 16) ? 61 : rt*4;
  int c0 = ct * CTN;
  float acc[RT][CTN] = {};
  mm_tile(aL, bL, r0, c0, acc);
  float* dst = Ctab + (size_t)v * REC;
  if (act) {
    #pragma unroll
    for (int q = 0; q < RT; ++q)
      #pragma unroll
      for (int u = 0; u < CTN; ++u) dst[(r0+q)*SP + c0 + u] = acc[q][u];
  }
  if (t < S) dst[t*SP + 65] = 0.f;   // zero pad column
}

// ---------- K3: segment chain product with rescaling
__global__ __launch_bounds__(NTH, 3) void k_seg(const float* __restrict__ Ctab,
    const float* __restrict__ em_pT, const int* __restrict__ obvs,
    float* __restrict__ Rseg, int* __restrict__ eacc_out, int NP) {
  __shared__ __align__(16) float Rb[2][REC];
  __shared__ __align__(16) float Cb[REC];
  __shared__ float evb[2][SP];
  __shared__ int smax[2];

  const int p = blockIdx.x, t = threadIdx.x;
  const int base = NP / PSEG, rem = NP % PSEG;
  const int k0 = p*base + (p < rem ? p : rem);
  const int L  = base + (p < rem ? 1 : 0);
  const int rt = t / CTILES, ct = t - rt*CTILES;
  const bool act = rt < RTILES;
  const int r0 = (rt >= 16) ? 61 : rt*4;      // clamp: all reads in-bounds
  const int c0 = ct * CTN;
  const int lane = t & 63;

  for (int u = t; u < REC; u += NTH) {
    int j = u / SP, k = u - j*SP;
    Rb[0][u] = (j == k && k < S) ? 1.f : 0.f; // identity, zero pads
    Rb[1][u] = 0.f;
  }
  if (t == 0) { smax[0] = 0; smax[1] = 0; }
  if (L > 0) {
    int o1 = obvs[1 + 2*k0], o2 = obvs[2 + 2*k0];
    const float* src = Ctab + (size_t)o1 * REC;
    for (int u = t; u < REC; u += NTH) Cb[u] = src[u];
    if (t < S) evb[0][t] = em_pT[(size_t)o2 * EMS + t];
  }
  __syncthreads();

  int cur = 0;
  int my_eacc = 0;
  for (int s = 0; s < L; ++s) {
    // --- stage next C + ev into registers (T14: issue early, write late)
    int kn = k0 + s + 1; if (kn > NP - 1) kn = NP - 1;
    int o1n = obvs[1 + 2*kn], o2n = obvs[2 + 2*kn];
    const float2* src2 = (const float2*)(Ctab + (size_t)o1n * REC);
    float2 creg[9];
    #pragma unroll
    for (int q = 0; q < 9; ++q) {
      int u = t + q*NTH;
      creg[q] = (u < REC/2) ? src2[u] : make_float2(0.f, 0.f);
    }
    float evreg = (t < S) ? em_pT[(size_t)o2n * EMS + t] : 0.f;

    // --- matmul R_new = R * C
    float acc[RT][CTN] = {};
    mm_tile(Rb[cur], Cb, r0, c0, acc);

    // --- block max (pre-emission) for power-of-2 rescale
    float mx = 0.f;
    if (act) {
      #pragma unroll
      for (int q = 0; q < RT; ++q)
        #pragma unroll
        for (int u = 0; u < CTN; ++u) mx = fmaxf(mx, acc[q][u]);
    }
    mx = wave_max(mx);
    if (lane == 0) atomicMax(&smax[s & 1], __float_as_int(mx));
    __syncthreads();                          // barrier A

    // --- write staged C/ev (matmul reads of Cb complete)
    {
      float2* dst2 = (float2*)Cb;
      #pragma unroll
      for (int q = 0; q < 9; ++q) {
        int u = t + q*NTH;
        if (u < REC/2) dst2[u] = creg[q];
      }
      if (t < S) evb[(s+1) & 1][t] = evreg;
    }
    int bm = smax[s & 1];
    int e = (bm >> 23) - 127;
    float scale = __int_as_float((127 - e) << 23);   // exact 2^-e
    if (t == 0) smax[(s+1) & 1] = 0;
    my_eacc += e;
    if (act) {
      float* rdst = Rb[cur ^ 1];
      #pragma unroll
      for (int u = 0; u < CTN; ++u) {
        float evs = evb[s & 1][c0 + u] * scale;
        #pragma unroll
        for (int q = 0; q < RT; ++q) rdst[(r0+q)*SP + c0 + u] = acc[q][u] * evs;
      }
    }
    __syncthreads();                          // barrier B
    cur ^= 1;
  }

  float* dst = Rseg + (size_t)p * REC;
  for (int u = t; u < REC; u += NTH) dst[u] = Rb[cur][u];
  if (t == 0) eacc_out[p] = my_eacc;
}

// ---------- K4: chain 12 consecutive segment matrices per block
__global__ __launch_bounds__(NTH) void k_chain(const float* __restrict__ Rseg,
    float* __restrict__ Rm, int* __restrict__ eacc2) {
  __shared__ __align__(16) float Rb[2][REC];
  __shared__ __align__(16) float Cb[REC];
  __shared__ int smax[2];
  const int g = blockIdx.x, t = threadIdx.x;
  const int rt = t / CTILES, ct = t - rt*CTILES;
  const bool act = rt < RTILES;
  const int r0 = (rt >= 16) ? 61 : rt*4;
  const int c0 = ct * CTN;
  const int lane = t & 63;
  {
    const float* src = Rseg + (size_t)(g*GROUP) * REC;
    for (int u = t; u < REC; u += NTH) { Rb[0][u] = src[u]; Rb[1][u] = 0.f; }
  }
  if (t == 0) { smax[0] = 0; smax[1] = 0; }
  __syncthreads();
  int cur = 0, my_e = 0;
  for (int q2 = 1; q2 < GROUP; ++q2) {
    const float* src = Rseg + (size_t)(g*GROUP + q2) * REC;
    for (int u = t; u < REC; u += NTH) Cb[u] = src[u];
    __syncthreads();                          // B1
    float acc[RT][CTN] = {};
    mm_tile(Rb[cur], Cb, r0, c0, acc);
    float mx = 0.f;
    if (act) {
      #pragma unroll
      for (int q = 0; q < RT; ++q)
        #pragma unroll
        for (int u = 0; u < CTN; ++u) mx = fmaxf(mx, acc[q][u]);
    }
    mx = wave_max(mx);
    if (lane == 0) atomicMax(&smax[q2 & 1], __float_as_int(mx));
    __syncthreads();                          // B2
    int bm = smax[q2 & 1];
    int e = (bm >> 23) - 127;
    float scale = __int_as_float((127 - e) << 23);
    my_e += e;
    if (t == 0) smax[(q2+1) & 1] = 0;
    if (act) {
      float* rdst = Rb[cur ^ 1];
      #pragma unroll
      for (int q = 0; q < RT; ++q)
        #pragma unroll
        for (int u = 0; u < CTN; ++u) rdst[(r0+q)*SP + c0 + u] = acc[q][u] * scale;
    }
    cur ^= 1;
  }
  __syncthreads();
  for (int u = t; u < REC; u += NTH) Rm[(size_t)g*REC + u] = Rb[cur][u];
  if (t == 0) eacc2[g] = my_e;
}

// ---------- K5: final vector sweep + termination + log (single block)
__global__ __launch_bounds__(NTH) void k_final(const float* __restrict__ Rm,
    const float* __restrict__ lt, const int* __restrict__ e1, const int* __restrict__ e2,
    const float* __restrict__ a_prob, const float* __restrict__ em_pT,
    const int* __restrict__ obvs, float* __restrict__ out, int N) {
  __shared__ __align__(16) float Mb[2][REC];
  __shared__ float vL[SP];
  __shared__ float prod[SP];
  __shared__ int smax[2];
  __shared__ int esum_s;
  const int t = threadIdx.x, lane = t & 63;
  if (t == 0) { esum_s = 0; smax[0] = 0; smax[1] = 0; }
  if (t < S) vL[t] = (t == 0) ? 1.f : expf(-20.0f);   // exp(log_pi)
  for (int u = t; u < REC; u += NTH) Mb[0][u] = Rm[u];
  __syncthreads();
  {
    int es = 0;
    for (int u = t; u < PSEG; u += NTH) es += e1[u];
    for (int u = t; u < NGROUPS; u += NTH) es += e2[u];
    es = wave_sumi(es);
    if (lane == 0) atomicAdd(&esum_s, es);
  }
  int cur = 0, my_e = 0;
  for (int m = 0; m < NGROUPS; ++m) {
    if (m + 1 < NGROUPS) {
      const float* src = Rm + (size_t)(m+1) * REC;
      for (int u = t; u < REC; u += NTH) Mb[cur ^ 1][u] = src[u];
    }
    float acc = 0.f;
    if (t < S) {
      const float* Mp = Mb[cur];
      #pragma unroll 5
      for (int i = 0; i < S; ++i) acc = fmaf(vL[i], Mp[i*SP + t], acc);
    }
    float mx = (t < S) ? acc : 0.f;
    mx = wave_max(mx);
    if (lane == 0) atomicMax(&smax[m & 1], __float_as_int(mx));
    __syncthreads();                          // (1)
    int bm = smax[m & 1];
    int e = (bm >> 23) - 127;
    float scale = __int_as_float((127 - e) << 23);
    my_e += e;
    if (t == 0) smax[(m+1) & 1] = 0;
    if (t < S) vL[t] = acc * scale;
    __syncthreads();                          // (2)
    cur ^= 1;
  }
  if (N & 1) {                                // leftover unpaired step
    int oN = obvs[N];
    float acc2 = 0.f;
    if (t < S) {
      #pragma unroll 5
      for (int i = 0; i < S; ++i) acc2 = fmaf(vL[i], a_prob[i*SP + t], acc2);
      acc2 *= em_pT[(size_t)oN * EMS + t];
    }
    __syncthreads();
    if (t < S) vL[t] = acc2;
    __syncthreads();
  }
  if (t < S) prod[t] = vL[t] * expf(lt[t*S]);  // raw log_trans[:,0]
  __syncthreads();
  if (t == 0) {
    double z = 0.0;
    for (int i = 0; i < S; ++i) z += (double)prod[i];
    double logz = log(z) + (double)(esum_s + my_e) * 0.69314718055994530942;
    out[0] = (float)logz;
  }
}

extern "C" void kernel_launch(void* const* d_in, const int* in_sizes, int n_in,
                              void* d_out, int out_size, void* d_ws, size_t ws_size,
                              hipStream_t stream) {
  (void)n_in; (void)out_size;
  const int*   obvs = (const int*)d_in[0];
  const float* lt   = (const float*)d_in[1];
  const float* le   = (const float*)d_in[2];
  float* out = (float*)d_out;
  const int T  = in_sizes[0];
  const int N  = T - 2;          // scan length
  const int NP = N >> 1;         // pair count

  float* ws = (float*)d_ws;
  size_t off = 0;
  float* a_prob = ws + off; off += 4292;                    // REC rounded to 16B
  float* em_pT  = ws + off; off += (size_t)VOCAB * EMS;     // 69632
  float* Ctab   = ws + off; off += (size_t)VOCAB * REC;     // 4,392,960
  float* Rseg   = ws + off; off += (size_t)PSEG * REC;      // 3,294,720
  float* Rm     = ws + off; off += (size_t)NGROUPS * REC;   // 274,560
  int* e1 = (int*)(ws + off); off += PSEG;
  int* e2 = (int*)(ws + off); off += NGROUPS;
  if (ws_size < off * sizeof(float)) return;                // ~31 MiB needed

  k_trans_prep<<<dim3(S), dim3(64), 0, stream>>>(lt, a_prob);
  k_em_prep  <<<dim3(S), dim3(NTH), 0, stream>>>(le, em_pT);
  k_pair     <<<dim3(VOCAB), dim3(NTH), 0, stream>>>(a_prob, em_pT, Ctab);
  k_seg      <<<dim3(PSEG), dim3(NTH), 0, stream>>>(Ctab, em_pT, obvs, Rseg, e1, NP);
  k_chain    <<<dim3(NGROUPS), dim3(NTH), 0, stream>>>(Rseg, Rm, e2);
  k_final    <<<dim3(1), dim3(NTH), 0, stream>>>(Rm, lt, e1, e2, a_prob, em_pT, obvs, out, N);
}